// Round 11
// baseline (127.476 us; speedup 1.0000x reference)
//
#include <hip/hip_runtime.h>
#include <cstdint>
#include <cstddef>

#define PRE_NMS  300
#define POST_K   100
#define NBUCKET  4096
#define CAND_MAX 2048
#define NCHUNK   16
#define SUB      128          // per-chunk candidate capacity (expected ~26)
#define NWORDS   5            // ceil(300/64)
#define KCAP     192          // capped NMS horizon (3 words); fallback if exhausted
#define KW       3            // capped word count
#define SUP_STRIDE 8          // row stride (u64): 64B rows
#define NBUK     512          // rank buckets
#define MBASE    0xC0800000u  // ~bits(1.0-) : min key-high for s in [FAST_T,1)
#define NMS_T    0.3f
#define SCORE_T  0.05f
#define FAST_T   0.9875f      // static fast-path threshold; fallback if <300 pass

typedef unsigned long long u64;

__device__ __forceinline__ float4 decode_box(float4 bo, float4 de,
                                             float wmax, float hmax) {
    float w  = bo.z - bo.x + 1.0f;
    float hh = bo.w - bo.y + 1.0f;
    float cx = bo.x + 0.5f * w;
    float cy = bo.y + 0.5f * hh;
    float pcx = de.x * 0.1f * w + cx;
    float pcy = de.y * 0.1f * hh + cy;
    float pw  = expf(de.z * 0.2f) * w;
    float ph  = expf(de.w * 0.2f) * hh;
    float x1 = fminf(fmaxf(pcx - 0.5f * pw, 0.0f), wmax);
    float y1 = fminf(fmaxf(pcy - 0.5f * ph, 0.0f), hmax);
    float x2 = fminf(fmaxf(pcx + 0.5f * pw, 0.0f), wmax);
    float y2 = fminf(fmaxf(pcy + 0.5f * ph, 0.0f), hmax);
    return make_float4(x1, y1, x2, y2);
}

// ---------------------------------------------------------------------------
// Kernel A: wide scan + DECODE. Candidate threads decode immediately (high
// occupancy hides the gather latency) and publish (key, box) per chunk.
// NO global atomics. grid = B*NCHUNK x 256.
// ---------------------------------------------------------------------------
__global__ __launch_bounds__(256) void scan_kernel(
    const float* __restrict__ cls_prob,   // B,N,2
    const float* __restrict__ boxes,      // B,N,4
    const float* __restrict__ deltas,     // B,N,4
    const float* __restrict__ im_info,    // B,3
    u64* __restrict__ keyG,               // B x NCHUNK x SUB
    float4* __restrict__ boxG,            // B x NCHUNK x SUB
    int* __restrict__ cntG,               // B x NCHUNK
    int N)
{
    const int b     = blockIdx.x >> 4;
    const int chunk = blockIdx.x & (NCHUNK - 1);
    const int nq    = N / 2;              // one float4 = 2 proposals
    const int per   = (nq + NCHUNK - 1) / NCHUNK;
    const int base  = chunk * per;
    const int end   = min(base + per, nq);

    __shared__ int lcnt;
    __shared__ u64 lk[SUB];
    __shared__ float4 lb[SUB];
    if (threadIdx.x == 0) lcnt = 0;
    __syncthreads();

    const float hmax = im_info[b * 3 + 0] - 1.0f;
    const float wmax = im_info[b * 3 + 1] - 1.0f;
    const float4* cp = (const float4*)(cls_prob + (size_t)b * N * 2);
    for (int q = base + threadIdx.x; q < end; q += 256) {
        float4 v = cp[q];
        #pragma unroll
        for (int h = 0; h < 2; ++h) {
            float s = h ? v.w : v.y;
            if (s >= FAST_T) {
                int pos = atomicAdd(&lcnt, 1);          // LDS atomic: cheap
                if (pos < SUB) {
                    int idx = 2 * q + h;
                    unsigned int m = __float_as_uint(s) ^ 0xFFFFFFFFu;
                    float4 bo = *(const float4*)(boxes  + ((size_t)b * N + idx) * 4);
                    float4 de = *(const float4*)(deltas + ((size_t)b * N + idx) * 4);
                    lk[pos] = ((u64)m << 32) | (unsigned int)idx;
                    lb[pos] = decode_box(bo, de, wmax, hmax);
                }
            }
        }
    }
    __syncthreads();

    const int cnt = lcnt;
    const size_t obase = (size_t)b * NCHUNK + chunk;
    u64* kb = keyG + obase * SUB;
    float4* bbo = boxG + obase * SUB;
    for (int i = threadIdx.x; i < min(cnt, SUB); i += 256) {
        kb[i]  = lk[i];
        bbo[i] = lb[i];
    }
    if (threadIdx.x == 0) cntG[obase] = cnt;  // raw (may exceed SUB)
}

// ---------------------------------------------------------------------------
// Kernel B: register-resident bucket-rank + capped ballot-sup + NMS.
// ---------------------------------------------------------------------------
__device__ __forceinline__ u64 keep_init_word(int Kv, int w) {
    int rem = Kv - 64 * w;
    if (rem >= 64) return ~0ull;
    if (rem <= 0)  return 0ull;
    return (1ull << rem) - 1ull;
}

__device__ __forceinline__ u64 bits_above(int b) {
    return (b == 63) ? 0ull : (~0ull << (b + 1));
}

__device__ __forceinline__ int key_bucket(u64 key) {
    unsigned int m = (unsigned int)(key >> 32);
    int d = (int)(m - MBASE);
    if (d < 0) return 0;
    int bu = d >> 9;
    return (bu > NBUK - 1) ? (NBUK - 1) : bu;
}

__device__ __forceinline__ float box_area(float4 v) {
    return (v.z - v.x + 1.0f) * (v.w - v.y + 1.0f);
}

__global__ __launch_bounds__(512) void proposal_kernel(
    const float* __restrict__ cls_prob,   // B,N,2
    const float* __restrict__ boxes,      // B,N,4
    const float* __restrict__ deltas,     // B,N,4
    const float* __restrict__ im_info,    // B,3
    float* __restrict__ out,              // B,POST_K,5
    const u64* __restrict__ keyG,         // B x NCHUNK x SUB
    const float4* __restrict__ boxG,      // B x NCHUNK x SUB
    const int* __restrict__ cntG,         // B x NCHUNK
    int useWS, int N)
{
    const int b   = blockIdx.x;
    const int tid = threadIdx.x;
    const int NT  = 512;

    __shared__ u64 cand[CAND_MAX];                 // 16 KB: fallback staging;
    int* hist4k = (int*)cand;                      //   fast path: buckets alias here
    int* buk_off = (int*)cand;                     // NBUK ints
    int* buk_cnt = buk_off + NBUK;                 // NBUK ints
    __shared__ float4 bb[PRE_NMS];                 // decoded boxes at sorted rank
    __shared__ u64 supRow[PRE_NMS * SUP_STRIDE];   // 19.2 KB (aliased as skey2)
    u64* skey2 = supRow;                           // bucket-grouped keys
    __shared__ u64 keepw[NWORDS];
    __shared__ int sel[POST_K];
    __shared__ int ws8[8];
    __shared__ int n_out;
    __shared__ int need_full;
    __shared__ int sh_cc;
    __shared__ int sh_ok;
    __shared__ int cand_count;
    __shared__ int cutoff;
    __shared__ int ccnt[NCHUNK], coff[NCHUNK + 1];

    if (tid == 0) { cand_count = 0; need_full = 0; }
    __syncthreads();

    const float4* cp = (const float4*)(cls_prob + (size_t)b * N * 2);
    const int nq = N / 2;
    const float hmax = im_info[b * 3 + 0] - 1.0f;
    const float wmax = im_info[b * 3 + 1] - 1.0f;

    // ---- 1. counts + gate: fast path needs all chunks intact and cc<=512 ----
    if (useWS && tid < NCHUNK) ccnt[tid] = cntG[b * NCHUNK + tid];
    __syncthreads();
    if (tid == 0) {
        int ok = useWS;
        int tot = 0;
        if (useWS) {
            for (int c = 0; c < NCHUNK; ++c) {
                if (ccnt[c] > SUB) ok = 0;
                coff[c] = tot;
                tot += ccnt[c];
            }
            coff[NCHUNK] = tot;
            if (tot < PRE_NMS || tot > NT) ok = 0;   // one cand per thread
        }
        sh_ok = ok;
        sh_cc = tot;
    }
    __syncthreads();
    const bool fast = (sh_ok != 0);
    int cc;

    if (fast) {
        cc = sh_cc;
        // ---- 2a. register-resident bucket rank ----
        buk_off[tid] = 0;                           // NBUK == NT
        buk_cnt[tid] = 0;
        if (tid < PRE_NMS) bb[tid] = make_float4(0.f, 0.f, 0.f, 0.f);
        __syncthreads();

        const bool have = (tid < cc);
        u64 my = 0; float4 mybox = make_float4(0.f, 0.f, 0.f, 0.f);
        int bu = 0;
        if (have) {
            int ch = 0;
            while (ch < NCHUNK - 1 && coff[ch + 1] <= tid) ++ch;
            size_t p = ((size_t)b * NCHUNK + ch) * SUB + (tid - coff[ch]);
            my = keyG[p];
            mybox = boxG[p];
            bu = key_bucket(my);
            atomicAdd(&buk_off[bu], 1);
        }
        __syncthreads();
        // block exclusive prefix sum over NBUK=512 counts (one value/thread)
        {
            int v = buk_off[tid];
            int lane = tid & 63;
            int incl = v;
            #pragma unroll
            for (int d = 1; d < 64; d <<= 1) {
                int nv = __shfl_up(incl, d, 64);
                if (lane >= d) incl += nv;
            }
            if (lane == 63) ws8[tid >> 6] = incl;
            __syncthreads();
            int woff = 0;
            #pragma unroll
            for (int w = 0; w < 8; ++w)
                if (w < (tid >> 6)) woff += ws8[w];
            __syncthreads();
            buk_off[tid] = woff + incl - v;          // exclusive offset
        }
        __syncthreads();
        if (have) skey2[buk_off[bu] + atomicAdd(&buk_cnt[bu], 1)] = my;
        __syncthreads();
        if (have) {
            int o = buk_off[bu], n = buk_cnt[bu];
            int r = o;
            for (int t = o; t < o + n; ++t) r += (skey2[t] < my) ? 1 : 0;
            if (r < PRE_NMS) bb[r] = mybox;          // rank is exact (keys unique)
        }
        __syncthreads();
    } else {
        // ---- 2b. full scan fallback (covers ws-overflow / cc>512 / no-ws) ----
        for (int q = tid; q < nq; q += NT) {
            float4 v = cp[q];
            #pragma unroll
            for (int h = 0; h < 2; ++h) {
                float s = h ? v.w : v.y;
                if (s >= FAST_T) {
                    int pos = atomicAdd(&cand_count, 1);
                    if (pos < CAND_MAX) {
                        unsigned int m = __float_as_uint(s) ^ 0xFFFFFFFFu;
                        cand[pos] = ((u64)m << 32) | (unsigned int)(2 * q + h);
                    }
                }
            }
        }
        __syncthreads();
        if (cand_count < PRE_NMS) {
            for (int i = tid; i < NBUCKET; i += NT) hist4k[i] = 0;
            __syncthreads();
            for (int q = tid; q < nq; q += NT) {
                float4 v = cp[q];
                if (v.y >= SCORE_T) atomicAdd(&hist4k[min((int)(v.y * (float)NBUCKET), NBUCKET - 1)], 1);
                if (v.w >= SCORE_T) atomicAdd(&hist4k[min((int)(v.w * (float)NBUCKET), NBUCKET - 1)], 1);
            }
            __syncthreads();
            if (tid == 0) {
                int acc = 0, c = 0;
                for (int i = NBUCKET - 1; i >= 0; --i) {
                    acc += hist4k[i];
                    if (acc >= PRE_NMS) { c = i; break; }
                }
                cutoff = c;
                cand_count = 0;
            }
            __syncthreads();
            const int c = cutoff;
            for (int q = tid; q < nq; q += NT) {
                float4 v = cp[q];
                #pragma unroll
                for (int h = 0; h < 2; ++h) {
                    float s = h ? v.w : v.y;
                    if (s >= SCORE_T) {
                        int bu = min((int)(s * (float)NBUCKET), NBUCKET - 1);
                        if (bu >= c) {
                            int pos = atomicAdd(&cand_count, 1);
                            if (pos < CAND_MAX) {
                                unsigned int m = __float_as_uint(s) ^ 0xFFFFFFFFu;
                                cand[pos] = ((u64)m << 32) | (unsigned int)(2 * q + h);
                            }
                        }
                    }
                }
            }
            __syncthreads();
        }
        cc = min(cand_count, CAND_MAX);
        if (tid == 0) sh_cc = cc;
        __syncthreads();
        cc = sh_cc;
        if (tid < PRE_NMS) bb[tid] = make_float4(0.f, 0.f, 0.f, 0.f);
        __syncthreads();
        // O(n^2) rank with fused gather+decode
        for (int c2 = tid; c2 < cc; c2 += NT) {
            u64 my = cand[c2];
            int r = 0;
            for (int k = 0; k < cc; ++k) r += (cand[k] < my) ? 1 : 0;
            if (r < PRE_NMS) {
                int idx = (int)(my & 0xFFFFFFFFull);
                float4 bo = *(const float4*)(boxes  + ((size_t)b * N + idx) * 4);
                float4 de = *(const float4*)(deltas + ((size_t)b * N + idx) * 4);
                bb[r] = decode_box(bo, de, wmax, hmax);
            }
        }
        __syncthreads();
    }

    const int Kv = min(cc, PRE_NMS);

    // ---- 3. CAPPED sup matrix via ballots: rows i < KCAP, words 0..KW-1 ----
    {
        const int lane = tid & 63;
        const int wv   = tid >> 6;                  // 0..7
        float4 cb[KW]; float ca[KW];
        #pragma unroll
        for (int g = 0; g < KW; ++g) {
            float4 v = bb[g * 64 + lane];           // j < 192 <= PRE_NMS
            cb[g] = v;
            ca[g] = box_area(v);
        }
        for (int i = wv; i < KCAP; i += 8) {
            float4 bi = bb[i];                      // broadcast
            float ai = box_area(bi);
            const int wi = i >> 6, bbit = i & 63;
            u64* rp = supRow + (size_t)i * SUP_STRIDE;
            #pragma unroll
            for (int g = 0; g < KW; ++g) {
                u64 word = 0;
                if (g >= wi) {
                    float xx1 = fmaxf(bi.x, cb[g].x);
                    float yy1 = fmaxf(bi.y, cb[g].y);
                    float xx2 = fminf(bi.z, cb[g].z);
                    float yy2 = fminf(bi.w, cb[g].w);
                    float iw = fmaxf(xx2 - xx1 + 1.0f, 0.0f);
                    float ih = fmaxf(yy2 - yy1 + 1.0f, 0.0f);
                    float inter = iw * ih;
                    bool ov = (inter > NMS_T * (ai + ca[g] - inter));
                    u64 bal = __ballot(ov);
                    word = (g == wi) ? (bal & bits_above(bbit)) : bal;
                }
                if (lane == 0) rp[g] = word;
            }
        }
    }
    __syncthreads();

    // ---- 4. capped greedy NMS: wave 0, 3 keep words, 4-way batched ----
    if (tid < 64) {
        u64 kw0 = keep_init_word(Kv, 0);
        u64 kw1 = keep_init_word(Kv, 1);
        u64 kw2 = keep_init_word(Kv, 2);

        int nk = 0;
        #pragma unroll
        for (int wi = 0; wi < KW; ++wi) {
            if (nk >= POST_K) break;
            u64 w = (wi == 0) ? kw0 : (wi == 1) ? kw1 : kw2;
            while (w != 0ull && nk < POST_K) {
                int b1 = __ffsll(w) - 1;
                u64 w1 = w & bits_above(b1);
                int b2 = (w1 != 0ull) ? (__ffsll(w1) - 1) : -1;
                u64 w2 = (b2 >= 0) ? (w1 & bits_above(b2)) : 0ull;
                int b3 = (w2 != 0ull) ? (__ffsll(w2) - 1) : -1;
                u64 w3 = (b3 >= 0) ? (w2 & bits_above(b3)) : 0ull;
                int b4 = (w3 != 0ull) ? (__ffsll(w3) - 1) : -1;

                const int base = wi * 64;
                const u64* p1 = supRow + (size_t)(base + b1) * SUP_STRIDE;
                const u64* p2 = supRow + (size_t)(base + ((b2 >= 0) ? b2 : b1)) * SUP_STRIDE;
                const u64* p3 = supRow + (size_t)(base + ((b3 >= 0) ? b3 : b1)) * SUP_STRIDE;
                const u64* p4 = supRow + (size_t)(base + ((b4 >= 0) ? b4 : b1)) * SUP_STRIDE;
                u64 a0 = p1[0], a1 = p1[1], a2 = p1[2];
                u64 c0 = p2[0], c1 = p2[1], c2 = p2[2];
                u64 d0 = p3[0], d1 = p3[1], d2 = p3[2];
                u64 e0 = p4[0], e1 = p4[1], e2 = p4[2];

                u64 aw = (wi == 0) ? a0 : (wi == 1) ? a1 : a2;
                u64 cw = (wi == 0) ? c0 : (wi == 1) ? c1 : c2;
                u64 dw = (wi == 0) ? d0 : (wi == 1) ? d1 : d2;

                kw0 &= ~a0; kw1 &= ~a1; kw2 &= ~a2;
                ++nk;
                bool k2 = false, k3 = false;
                if (b2 >= 0 && nk < POST_K && !((aw >> b2) & 1ull)) {
                    kw0 &= ~c0; kw1 &= ~c1; kw2 &= ~c2;
                    ++nk; k2 = true;
                }
                if (b3 >= 0 && nk < POST_K && !((aw >> b3) & 1ull)
                    && !(k2 && ((cw >> b3) & 1ull))) {
                    kw0 &= ~d0; kw1 &= ~d1; kw2 &= ~d2;
                    ++nk; k3 = true;
                }
                if (b4 >= 0 && nk < POST_K && !((aw >> b4) & 1ull)
                    && !(k2 && ((cw >> b4) & 1ull))
                    && !(k3 && ((dw >> b4) & 1ull))) {
                    kw0 &= ~e0; kw1 &= ~e1; kw2 &= ~e2;
                    ++nk;
                }
                int blast = (b4 >= 0) ? b4 : ((b3 >= 0) ? b3 : ((b2 >= 0) ? b2 : b1));
                u64 self = (wi == 0) ? kw0 : (wi == 1) ? kw1 : kw2;
                w = self & bits_above(blast);
            }
        }
        if (tid == 0) {
            keepw[0] = kw0; keepw[1] = kw1; keepw[2] = kw2;
            keepw[3] = 0ull; keepw[4] = 0ull;
            n_out = nk;
            need_full = (nk < POST_K && Kv > KCAP) ? 1 : 0;
        }
    }
    __syncthreads();

    // ---- 4b. EXACT fallback: full 300x5 sup + full NMS from scratch ----
    if (need_full) {
        for (int t = tid; t < PRE_NMS * NWORDS; t += NT) {
            int w = t / PRE_NMS;
            int i = t - w * PRE_NMS;
            int jbase = w * 64;
            int jend  = min(jbase + 64, PRE_NMS);
            u64 bits = 0;
            int jstart = max(jbase, i + 1);
            if (jstart < jend) {
                float4 bi = bb[i];
                float ai = box_area(bi);
                for (int j = jstart; j < jend; ++j) {
                    float4 bj = bb[j];
                    float aj = box_area(bj);
                    float xx1 = fmaxf(bi.x, bj.x);
                    float yy1 = fmaxf(bi.y, bj.y);
                    float xx2 = fminf(bi.z, bj.z);
                    float yy2 = fminf(bi.w, bj.w);
                    float iw = fmaxf(xx2 - xx1 + 1.0f, 0.0f);
                    float ih = fmaxf(yy2 - yy1 + 1.0f, 0.0f);
                    float inter = iw * ih;
                    if (inter > NMS_T * (ai + aj - inter)) bits |= (1ull << (j - jbase));
                }
            }
            supRow[i * SUP_STRIDE + w] = bits;
        }
        __syncthreads();
        if (tid == 0) {
            u64 kk[NWORDS];
            #pragma unroll
            for (int w = 0; w < NWORDS; ++w) kk[w] = keep_init_word(Kv, w);
            int nk = 0;
            for (int i = 0; i < PRE_NMS && nk < POST_K; ++i) {
                if ((kk[i >> 6] >> (i & 63)) & 1ull) {
                    const u64* r = supRow + (size_t)i * SUP_STRIDE;
                    #pragma unroll
                    for (int w = 0; w < NWORDS; ++w) kk[w] &= ~r[w];
                    ++nk;
                }
            }
            #pragma unroll
            for (int w = 0; w < NWORDS; ++w) keepw[w] = kk[w];
            n_out = nk;
        }
        __syncthreads();
    }

    // ---- 5. parallel compaction (cap via prefix < POST_K) ----
    if (tid < PRE_NMS) {
        int wi = tid >> 6, bi = tid & 63;
        u64 w = keepw[wi];
        int prefix = 0;
        #pragma unroll
        for (int ww = 0; ww < NWORDS; ++ww)
            if (ww < wi) prefix += __popcll(keepw[ww]);
        prefix += __popcll(w & ((1ull << bi) - 1ull));
        if (((w >> bi) & 1ull) && prefix < POST_K) sel[prefix] = tid;
    }
    __syncthreads();

    // ---- 6. output ----
    if (tid < POST_K) {
        float* op = out + ((size_t)b * POST_K + tid) * 5;
        op[0] = (float)b;
        if (tid < n_out) {
            float4 v = bb[sel[tid]];
            op[1] = v.x; op[2] = v.y; op[3] = v.z; op[4] = v.w;
        } else {
            op[1] = 0.0f; op[2] = 0.0f; op[3] = 0.0f; op[4] = 0.0f;
        }
    }
}

extern "C" void kernel_launch(void* const* d_in, const int* in_sizes, int n_in,
                              void* d_out, int out_size, void* d_ws, size_t ws_size,
                              hipStream_t stream) {
    const float* cls_prob = (const float*)d_in[0];
    const float* boxes    = (const float*)d_in[1];
    const float* deltas   = (const float*)d_in[2];
    const float* im_info  = (const float*)d_in[3];
    float* out = (float*)d_out;

    const int B = in_sizes[3] / 3;
    const int N = in_sizes[0] / (B * 2);

    const size_t nSlots = (size_t)B * NCHUNK * SUB;
    int*    cntG = (int*)d_ws;                            // B*NCHUNK ints (<=16KB)
    u64*    keyG = (u64*)((char*)d_ws + 16384);           // nSlots u64
    float4* boxG = (float4*)((char*)d_ws + 16384 + nSlots * sizeof(u64));
    size_t need = 16384 + nSlots * (sizeof(u64) + sizeof(float4));
    int useWS   = (ws_size >= need && B * NCHUNK * (int)sizeof(int) <= 16384) ? 1 : 0;

    if (useWS) {
        scan_kernel<<<B * NCHUNK, 256, 0, stream>>>(cls_prob, boxes, deltas, im_info,
                                                    keyG, boxG, cntG, N);
    }
    proposal_kernel<<<B, 512, 0, stream>>>(cls_prob, boxes, deltas, im_info, out,
                                           keyG, boxG, cntG, useWS, N);
}

// Round 12
// 117.938 us; speedup vs baseline: 1.0809x; 1.0809x over previous
//
#include <hip/hip_runtime.h>
#include <cstdint>
#include <cstddef>

#define PRE_NMS  300
#define POST_K   100
#define NBUCKET  4096
#define CAND_MAX 2048
#define NCHUNK   16
#define SUB      128          // per-chunk candidate capacity (expected ~26)
#define NWORDS   5            // ceil(300/64)
#define KCAP     192          // capped NMS horizon (3 words); fallback if exhausted
#define KW       3            // capped word count
#define SUP_STRIDE 8          // row stride (u64): 64B rows (fallback matrix)
#define NBUK     512          // rank buckets
#define MBASE    0xC0800000u  // ~bits(1.0-) : min key-high for s in [FAST_T,1)
#define NMS_T    0.3f
#define SCORE_T  0.05f
#define FAST_T   0.9875f      // static fast-path threshold; fallback if <300 pass

typedef unsigned long long u64;

__device__ __forceinline__ float4 decode_box(float4 bo, float4 de,
                                             float wmax, float hmax) {
    float w  = bo.z - bo.x + 1.0f;
    float hh = bo.w - bo.y + 1.0f;
    float cx = bo.x + 0.5f * w;
    float cy = bo.y + 0.5f * hh;
    float pcx = de.x * 0.1f * w + cx;
    float pcy = de.y * 0.1f * hh + cy;
    float pw  = expf(de.z * 0.2f) * w;
    float ph  = expf(de.w * 0.2f) * hh;
    float x1 = fminf(fmaxf(pcx - 0.5f * pw, 0.0f), wmax);
    float y1 = fminf(fmaxf(pcy - 0.5f * ph, 0.0f), hmax);
    float x2 = fminf(fmaxf(pcx + 0.5f * pw, 0.0f), wmax);
    float y2 = fminf(fmaxf(pcy + 0.5f * ph, 0.0f), hmax);
    return make_float4(x1, y1, x2, y2);
}

// ---------------------------------------------------------------------------
// Kernel A: wide scan + DECODE. grid = B*NCHUNK x 256. No global atomics.
// ---------------------------------------------------------------------------
__global__ __launch_bounds__(256) void scan_kernel(
    const float* __restrict__ cls_prob,   // B,N,2
    const float* __restrict__ boxes,      // B,N,4
    const float* __restrict__ deltas,     // B,N,4
    const float* __restrict__ im_info,    // B,3
    u64* __restrict__ keyG,               // B x NCHUNK x SUB
    float4* __restrict__ boxG,            // B x NCHUNK x SUB
    int* __restrict__ cntG,               // B x NCHUNK
    int N)
{
    const int b     = blockIdx.x >> 4;
    const int chunk = blockIdx.x & (NCHUNK - 1);
    const int nq    = N / 2;              // one float4 = 2 proposals
    const int per   = (nq + NCHUNK - 1) / NCHUNK;
    const int base  = chunk * per;
    const int end   = min(base + per, nq);

    __shared__ int lcnt;
    __shared__ u64 lk[SUB];
    __shared__ float4 lb[SUB];
    if (threadIdx.x == 0) lcnt = 0;
    __syncthreads();

    const float hmax = im_info[b * 3 + 0] - 1.0f;
    const float wmax = im_info[b * 3 + 1] - 1.0f;
    const float4* cp = (const float4*)(cls_prob + (size_t)b * N * 2);
    for (int q = base + threadIdx.x; q < end; q += 256) {
        float4 v = cp[q];
        #pragma unroll
        for (int h = 0; h < 2; ++h) {
            float s = h ? v.w : v.y;
            if (s >= FAST_T) {
                int pos = atomicAdd(&lcnt, 1);          // LDS atomic: cheap
                if (pos < SUB) {
                    int idx = 2 * q + h;
                    unsigned int m = __float_as_uint(s) ^ 0xFFFFFFFFu;
                    float4 bo = *(const float4*)(boxes  + ((size_t)b * N + idx) * 4);
                    float4 de = *(const float4*)(deltas + ((size_t)b * N + idx) * 4);
                    lk[pos] = ((u64)m << 32) | (unsigned int)idx;
                    lb[pos] = decode_box(bo, de, wmax, hmax);
                }
            }
        }
    }
    __syncthreads();

    const int cnt = lcnt;
    const size_t obase = (size_t)b * NCHUNK + chunk;
    u64* kb = keyG + obase * SUB;
    float4* bbo = boxG + obase * SUB;
    for (int i = threadIdx.x; i < min(cnt, SUB); i += 256) {
        kb[i]  = lk[i];
        bbo[i] = lb[i];
    }
    if (threadIdx.x == 0) cntG[obase] = cnt;  // raw (may exceed SUB)
}

// ---------------------------------------------------------------------------
// Kernel B: register bucket-rank + column-ballot + register fixpoint NMS.
// ---------------------------------------------------------------------------
__device__ __forceinline__ u64 keep_init_word(int Kv, int w) {
    int rem = Kv - 64 * w;
    if (rem >= 64) return ~0ull;
    if (rem <= 0)  return 0ull;
    return (1ull << rem) - 1ull;
}

__device__ __forceinline__ int key_bucket(u64 key) {
    unsigned int m = (unsigned int)(key >> 32);
    int d = (int)(m - MBASE);
    if (d < 0) return 0;
    int bu = d >> 9;
    return (bu > NBUK - 1) ? (NBUK - 1) : bu;
}

__device__ __forceinline__ float box_area(float4 v) {
    return (v.z - v.x + 1.0f) * (v.w - v.y + 1.0f);
}

__global__ __launch_bounds__(512) void proposal_kernel(
    const float* __restrict__ cls_prob,   // B,N,2
    const float* __restrict__ boxes,      // B,N,4
    const float* __restrict__ deltas,     // B,N,4
    const float* __restrict__ im_info,    // B,3
    float* __restrict__ out,              // B,POST_K,5
    const u64* __restrict__ keyG,         // B x NCHUNK x SUB
    const float4* __restrict__ boxG,      // B x NCHUNK x SUB
    const int* __restrict__ cntG,         // B x NCHUNK
    int useWS, int N)
{
    const int b   = blockIdx.x;
    const int tid = threadIdx.x;
    const int NT  = 512;

    __shared__ u64 cand[CAND_MAX];                 // 16 KB: fallback staging;
    int* hist4k = (int*)cand;                      //   fast path: buckets alias here
    int* buk_off = (int*)cand;                     // NBUK ints
    int* buk_cnt = buk_off + NBUK;                 // NBUK ints
    __shared__ float4 bb[PRE_NMS];                 // decoded boxes at sorted rank
    __shared__ u64 supRow[PRE_NMS * SUP_STRIDE];   // 19.2 KB (aliases skey2, colW)
    u64* skey2 = supRow;                           // bucket-grouped keys (rank phase)
    u64* colW  = supRow;                           // KCAP x 4 column words (NMS phase)
    __shared__ u64 keepw[NWORDS];
    __shared__ int sel[POST_K];
    __shared__ int ws8[8];
    __shared__ int n_out;
    __shared__ int need_full;
    __shared__ int sh_cc;
    __shared__ int sh_ok;
    __shared__ int cand_count;
    __shared__ int cutoff;
    __shared__ int ccnt[NCHUNK], coff[NCHUNK + 1];

    if (tid == 0) { cand_count = 0; need_full = 0; }
    __syncthreads();

    const float4* cp = (const float4*)(cls_prob + (size_t)b * N * 2);
    const int nq = N / 2;
    const float hmax = im_info[b * 3 + 0] - 1.0f;
    const float wmax = im_info[b * 3 + 1] - 1.0f;

    // ---- 1. counts + gate: fast path needs all chunks intact and cc<=512 ----
    if (useWS && tid < NCHUNK) ccnt[tid] = cntG[b * NCHUNK + tid];
    __syncthreads();
    if (tid == 0) {
        int ok = useWS;
        int tot = 0;
        if (useWS) {
            for (int c = 0; c < NCHUNK; ++c) {
                if (ccnt[c] > SUB) ok = 0;
                coff[c] = tot;
                tot += ccnt[c];
            }
            coff[NCHUNK] = tot;
            if (tot < PRE_NMS || tot > NT) ok = 0;   // one cand per thread
        }
        sh_ok = ok;
        sh_cc = tot;
    }
    __syncthreads();
    const bool fast = (sh_ok != 0);
    int cc;

    if (fast) {
        cc = sh_cc;
        // ---- 2a. register-resident bucket rank ----
        buk_off[tid] = 0;                           // NBUK == NT
        buk_cnt[tid] = 0;
        if (tid < PRE_NMS) bb[tid] = make_float4(0.f, 0.f, 0.f, 0.f);
        __syncthreads();

        const bool have = (tid < cc);
        u64 my = 0; float4 mybox = make_float4(0.f, 0.f, 0.f, 0.f);
        int bu = 0;
        if (have) {
            int ch = 0;
            while (ch < NCHUNK - 1 && coff[ch + 1] <= tid) ++ch;
            size_t p = ((size_t)b * NCHUNK + ch) * SUB + (tid - coff[ch]);
            my = keyG[p];
            mybox = boxG[p];
            bu = key_bucket(my);
            atomicAdd(&buk_off[bu], 1);
        }
        __syncthreads();
        // block exclusive prefix sum over NBUK=512 counts (one value/thread)
        {
            int v = buk_off[tid];
            int lane = tid & 63;
            int incl = v;
            #pragma unroll
            for (int d = 1; d < 64; d <<= 1) {
                int nv = __shfl_up(incl, d, 64);
                if (lane >= d) incl += nv;
            }
            if (lane == 63) ws8[tid >> 6] = incl;
            __syncthreads();
            int woff = 0;
            #pragma unroll
            for (int w = 0; w < 8; ++w)
                if (w < (tid >> 6)) woff += ws8[w];
            __syncthreads();
            buk_off[tid] = woff + incl - v;          // exclusive offset
        }
        __syncthreads();
        if (have) skey2[buk_off[bu] + atomicAdd(&buk_cnt[bu], 1)] = my;
        __syncthreads();
        if (have) {
            int o = buk_off[bu], n = buk_cnt[bu];
            int r = o;
            for (int t = o; t < o + n; ++t) r += (skey2[t] < my) ? 1 : 0;
            if (r < PRE_NMS) bb[r] = mybox;          // rank is exact (keys unique)
        }
        __syncthreads();
    } else {
        // ---- 2b. full scan fallback (covers ws-overflow / cc>512 / no-ws) ----
        for (int q = tid; q < nq; q += NT) {
            float4 v = cp[q];
            #pragma unroll
            for (int h = 0; h < 2; ++h) {
                float s = h ? v.w : v.y;
                if (s >= FAST_T) {
                    int pos = atomicAdd(&cand_count, 1);
                    if (pos < CAND_MAX) {
                        unsigned int m = __float_as_uint(s) ^ 0xFFFFFFFFu;
                        cand[pos] = ((u64)m << 32) | (unsigned int)(2 * q + h);
                    }
                }
            }
        }
        __syncthreads();
        if (cand_count < PRE_NMS) {
            for (int i = tid; i < NBUCKET; i += NT) hist4k[i] = 0;
            __syncthreads();
            for (int q = tid; q < nq; q += NT) {
                float4 v = cp[q];
                if (v.y >= SCORE_T) atomicAdd(&hist4k[min((int)(v.y * (float)NBUCKET), NBUCKET - 1)], 1);
                if (v.w >= SCORE_T) atomicAdd(&hist4k[min((int)(v.w * (float)NBUCKET), NBUCKET - 1)], 1);
            }
            __syncthreads();
            if (tid == 0) {
                int acc = 0, c = 0;
                for (int i = NBUCKET - 1; i >= 0; --i) {
                    acc += hist4k[i];
                    if (acc >= PRE_NMS) { c = i; break; }
                }
                cutoff = c;
                cand_count = 0;
            }
            __syncthreads();
            const int c = cutoff;
            for (int q = tid; q < nq; q += NT) {
                float4 v = cp[q];
                #pragma unroll
                for (int h = 0; h < 2; ++h) {
                    float s = h ? v.w : v.y;
                    if (s >= SCORE_T) {
                        int bu = min((int)(s * (float)NBUCKET), NBUCKET - 1);
                        if (bu >= c) {
                            int pos = atomicAdd(&cand_count, 1);
                            if (pos < CAND_MAX) {
                                unsigned int m = __float_as_uint(s) ^ 0xFFFFFFFFu;
                                cand[pos] = ((u64)m << 32) | (unsigned int)(2 * q + h);
                            }
                        }
                    }
                }
            }
            __syncthreads();
        }
        cc = min(cand_count, CAND_MAX);
        if (tid == 0) sh_cc = cc;
        __syncthreads();
        cc = sh_cc;
        if (tid < PRE_NMS) bb[tid] = make_float4(0.f, 0.f, 0.f, 0.f);
        __syncthreads();
        // O(n^2) rank with fused gather+decode
        for (int c2 = tid; c2 < cc; c2 += NT) {
            u64 my = cand[c2];
            int r = 0;
            for (int k = 0; k < cc; ++k) r += (cand[k] < my) ? 1 : 0;
            if (r < PRE_NMS) {
                int idx = (int)(my & 0xFFFFFFFFull);
                float4 bo = *(const float4*)(boxes  + ((size_t)b * N + idx) * 4);
                float4 de = *(const float4*)(deltas + ((size_t)b * N + idx) * 4);
                bb[r] = decode_box(bo, de, wmax, hmax);
            }
        }
        __syncthreads();
    }

    const int Kv = min(cc, PRE_NMS);

    // ---- 3. COLUMN ballots: colW[j][g] = bits i in word g with
    //      IoU(i,j)>T and i<j  (pre-masked below-diagonal). Lanes index i. ----
    {
        const int lane = tid & 63;
        const int wv   = tid >> 6;                  // 0..7
        float4 cb[KW]; float ca[KW];
        #pragma unroll
        for (int g = 0; g < KW; ++g) {
            float4 v = bb[g * 64 + lane];           // i < 192 <= PRE_NMS
            cb[g] = v;
            ca[g] = box_area(v);
        }
        for (int j = wv; j < KCAP; j += 8) {
            float4 bj = bb[j];                      // broadcast
            float aj = box_area(bj);
            const int jw = j >> 6, jb = j & 63;
            u64* cpw = colW + (size_t)j * 4;
            #pragma unroll
            for (int g = 0; g < KW; ++g) {
                u64 word = 0;
                if (g <= jw) {
                    float xx1 = fmaxf(bj.x, cb[g].x);
                    float yy1 = fmaxf(bj.y, cb[g].y);
                    float xx2 = fminf(bj.z, cb[g].z);
                    float yy2 = fminf(bj.w, cb[g].w);
                    float iw = fmaxf(xx2 - xx1 + 1.0f, 0.0f);
                    float ih = fmaxf(yy2 - yy1 + 1.0f, 0.0f);
                    float inter = iw * ih;
                    bool ov = (inter > NMS_T * (aj + ca[g] - inter));
                    u64 bal = __ballot(ov);
                    word = (g == jw) ? (bal & ((1ull << jb) - 1ull)) : bal;
                }
                if (lane == 0) cpw[g] = word;
            }
        }
    }
    __syncthreads();

    // ---- 4. fixpoint NMS in wave 0 registers: alive = F(alive) until stable.
    //      Any fixpoint of F equals greedy keep (induction on j). Barrier-free:
    //      alive words rebuilt by ballot each sweep (~50 cyc/sweep, ~3 sweeps). ----
    if (tid < 64) {
        const int lane = tid;
        u64 c00 = colW[(size_t)lane * 4 + 0];
        u64 c10 = colW[(size_t)(64 + lane) * 4 + 0];
        u64 c11 = colW[(size_t)(64 + lane) * 4 + 1];
        u64 c20 = colW[(size_t)(128 + lane) * 4 + 0];
        u64 c21 = colW[(size_t)(128 + lane) * 4 + 1];
        u64 c22 = colW[(size_t)(128 + lane) * 4 + 2];

        u64 kv0 = keep_init_word(Kv, 0);
        u64 kv1 = keep_init_word(Kv, 1);
        u64 kv2 = keep_init_word(Kv, 2);
        bool v0 = (kv0 >> lane) & 1ull;
        bool v1 = (kv1 >> lane) & 1ull;
        bool v2 = (kv2 >> lane) & 1ull;
        bool b0 = v0, b1 = v1, b2 = v2;

        for (int it = 0; it < KCAP + 8; ++it) {
            u64 w0 = __ballot(b0);
            u64 w1 = __ballot(b1);
            u64 w2 = __ballot(b2);
            bool n0 = v0 && (((w0 & c00)) == 0ull);
            bool n1 = v1 && (((w0 & c10) | (w1 & c11)) == 0ull);
            bool n2 = v2 && (((w0 & c20) | (w1 & c21) | (w2 & c22)) == 0ull);
            u64 ch = __ballot(n0 != b0 || n1 != b1 || n2 != b2);
            b0 = n0; b1 = n1; b2 = n2;
            if (ch == 0ull) break;
        }
        u64 f0 = __ballot(b0);
        u64 f1 = __ballot(b1);
        u64 f2 = __ballot(b2);
        if (lane == 0) {
            keepw[0] = f0; keepw[1] = f1; keepw[2] = f2;
            keepw[3] = 0ull; keepw[4] = 0ull;
            int nk = __popcll(f0) + __popcll(f1) + __popcll(f2);
            n_out = (nk < POST_K) ? nk : POST_K;
            need_full = (nk < POST_K && Kv > KCAP) ? 1 : 0;
        }
    }
    __syncthreads();

    // ---- 4b. EXACT fallback: full 300x5 sup + full NMS from scratch ----
    if (need_full) {
        for (int t = tid; t < PRE_NMS * NWORDS; t += NT) {
            int w = t / PRE_NMS;
            int i = t - w * PRE_NMS;
            int jbase = w * 64;
            int jend  = min(jbase + 64, PRE_NMS);
            u64 bits = 0;
            int jstart = max(jbase, i + 1);
            if (jstart < jend) {
                float4 bi = bb[i];
                float ai = box_area(bi);
                for (int j = jstart; j < jend; ++j) {
                    float4 bj = bb[j];
                    float aj = box_area(bj);
                    float xx1 = fmaxf(bi.x, bj.x);
                    float yy1 = fmaxf(bi.y, bj.y);
                    float xx2 = fminf(bi.z, bj.z);
                    float yy2 = fminf(bi.w, bj.w);
                    float iw = fmaxf(xx2 - xx1 + 1.0f, 0.0f);
                    float ih = fmaxf(yy2 - yy1 + 1.0f, 0.0f);
                    float inter = iw * ih;
                    if (inter > NMS_T * (ai + aj - inter)) bits |= (1ull << (j - jbase));
                }
            }
            supRow[i * SUP_STRIDE + w] = bits;
        }
        __syncthreads();
        if (tid == 0) {
            u64 kk[NWORDS];
            #pragma unroll
            for (int w = 0; w < NWORDS; ++w) kk[w] = keep_init_word(Kv, w);
            int nk = 0;
            for (int i = 0; i < PRE_NMS && nk < POST_K; ++i) {
                if ((kk[i >> 6] >> (i & 63)) & 1ull) {
                    const u64* r = supRow + (size_t)i * SUP_STRIDE;
                    #pragma unroll
                    for (int w = 0; w < NWORDS; ++w) kk[w] &= ~r[w];
                    ++nk;
                }
            }
            #pragma unroll
            for (int w = 0; w < NWORDS; ++w) keepw[w] = kk[w];
            n_out = nk;
        }
        __syncthreads();
    }

    // ---- 5. parallel compaction (cap via prefix < POST_K) ----
    if (tid < PRE_NMS) {
        int wi = tid >> 6, bi = tid & 63;
        u64 w = keepw[wi];
        int prefix = 0;
        #pragma unroll
        for (int ww = 0; ww < NWORDS; ++ww)
            if (ww < wi) prefix += __popcll(keepw[ww]);
        prefix += __popcll(w & ((1ull << bi) - 1ull));
        if (((w >> bi) & 1ull) && prefix < POST_K) sel[prefix] = tid;
    }
    __syncthreads();

    // ---- 6. output ----
    if (tid < POST_K) {
        float* op = out + ((size_t)b * POST_K + tid) * 5;
        op[0] = (float)b;
        if (tid < n_out) {
            float4 v = bb[sel[tid]];
            op[1] = v.x; op[2] = v.y; op[3] = v.z; op[4] = v.w;
        } else {
            op[1] = 0.0f; op[2] = 0.0f; op[3] = 0.0f; op[4] = 0.0f;
        }
    }
}

extern "C" void kernel_launch(void* const* d_in, const int* in_sizes, int n_in,
                              void* d_out, int out_size, void* d_ws, size_t ws_size,
                              hipStream_t stream) {
    const float* cls_prob = (const float*)d_in[0];
    const float* boxes    = (const float*)d_in[1];
    const float* deltas   = (const float*)d_in[2];
    const float* im_info  = (const float*)d_in[3];
    float* out = (float*)d_out;

    const int B = in_sizes[3] / 3;
    const int N = in_sizes[0] / (B * 2);

    const size_t nSlots = (size_t)B * NCHUNK * SUB;
    int*    cntG = (int*)d_ws;                            // B*NCHUNK ints (<=16KB)
    u64*    keyG = (u64*)((char*)d_ws + 16384);           // nSlots u64
    float4* boxG = (float4*)((char*)d_ws + 16384 + nSlots * sizeof(u64));
    size_t need = 16384 + nSlots * (sizeof(u64) + sizeof(float4));
    int useWS   = (ws_size >= need && B * NCHUNK * (int)sizeof(int) <= 16384) ? 1 : 0;

    if (useWS) {
        scan_kernel<<<B * NCHUNK, 256, 0, stream>>>(cls_prob, boxes, deltas, im_info,
                                                    keyG, boxG, cntG, N);
    }
    proposal_kernel<<<B, 512, 0, stream>>>(cls_prob, boxes, deltas, im_info, out,
                                           keyG, boxG, cntG, useWS, N);
}